// Round 11
// baseline (856.287 us; speedup 1.0000x reference)
//
#include <hip/hip_runtime.h>
#include <hip/hip_bf16.h>
#include <math.h>

#define NN 8192
#define EE 131072
#define HH 256
#define LL 3
#define RR 128
#define NGG 64
#define MSG_WAVES 8          // waves per k_msg block (512 threads; 2 blocks/CU)

typedef __attribute__((ext_vector_type(8))) short bf16x8;
typedef __attribute__((ext_vector_type(4))) float f32x4;
typedef unsigned short u16;

#if defined(__has_builtin)
#if __has_builtin(__builtin_amdgcn_fdot2_f32_bf16)
#define HAVE_FDOT2 1
typedef __attribute__((ext_vector_type(2))) __bf16 bf16x2_t;
union BU { unsigned u; bf16x2_t v; };
#endif
#if __has_builtin(__builtin_amdgcn_global_load_lds)
#define HAVE_GLL 1
#endif
#endif

union U4 { ushort4 v; unsigned short a[4]; };
union U8 { uint4 v; unsigned short a[8]; unsigned w[4]; };

__device__ __forceinline__ float silu(float v) { return v / (1.0f + expf(-v)); }
__device__ __forceinline__ float b2f(unsigned short u) { return __uint_as_float(((unsigned)u) << 16); }
__device__ __forceinline__ unsigned short f2b(float f) {
    unsigned u = __float_as_uint(f);
    u += 0x7fff + ((u >> 16) & 1);
    return (unsigned short)(u >> 16);
}

constexpr float kInvSqrt2 = 0.70710678118654752440f;
constexpr float kInvSqrt3 = 0.57735026918962576451f;
constexpr float kInvSqrtH = 0.0625f; // 1/sqrt(256)

// ---------------- utility ----------------
__global__ void k_zero(float* __restrict__ p, int n4) {
    int i = blockIdx.x * 256 + threadIdx.x;
    if (i < n4) ((float4*)p)[i] = make_float4(0.f, 0.f, 0.f, 0.f);
}

// ---------------- ALL weight prep in one launch ----------------
// transpose in[K,N] fp32 -> out[N,K] bf16; rbf_w: row-PAIR interleaved k-major bf16
__global__ __launch_bounds__(256) void k_wt_all(
    const float* __restrict__ xp_w1, const float* __restrict__ xp_w2,
    const float* __restrict__ rbf_w, const float* __restrict__ vec_w,
    const float* __restrict__ xv_w1, const float* __restrict__ xv_w2,
    const float* __restrict__ oe_w1,
    u16* __restrict__ xp_w1T, u16* __restrict__ xp_w2T, u16* __restrict__ rbf_wP,
    u16* __restrict__ vec_wT, u16* __restrict__ xv_w1T, u16* __restrict__ xv_w2T,
    u16* __restrict__ oe_w1T) {
    int bid = blockIdx.x;
    const float* src; u16* dst; int K, N, t, pairmode = 0;
    if (bid < 2400) {
        int l = bid / 800, r = bid % 800;
        if (r < 64)       { src = xp_w1 + (size_t)l * 65536;  dst = xp_w1T + (size_t)l * 65536;  K = 256; N = 256; t = r; }
        else if (r < 256) { src = xp_w2 + (size_t)l * 196608; dst = xp_w2T + (size_t)l * 196608; K = 256; N = 768; t = r - 64; }
        else if (r < 352) { src = rbf_w + (size_t)l * 98304;  dst = rbf_wP + (size_t)l * 98304;  K = 128; N = 768; t = r - 256; pairmode = 1; }
        else if (r < 480) { src = vec_w + (size_t)l * 131072; dst = vec_wT + (size_t)l * 131072; K = 256; N = 512; t = r - 352; }
        else if (r < 608) { src = xv_w1 + (size_t)l * 131072; dst = xv_w1T + (size_t)l * 131072; K = 512; N = 256; t = r - 480; }
        else              { src = xv_w2 + (size_t)l * 196608; dst = xv_w2T + (size_t)l * 196608; K = 256; N = 768; t = r - 608; }
    } else {
        src = oe_w1; dst = oe_w1T; K = 256; N = 128; t = bid - 2400;
    }
    int nx = N >> 5;
    int bn = (t % nx) * 32, bk = (t / nx) * 32;
    int tx = threadIdx.x & 31, ty = threadIdx.x >> 5;   // 32 x 8
    if (pairmode) {
#pragma unroll
        for (int i = 0; i < 32; i += 8) {
            int k = bk + ty + i, n = bn + tx;
            dst[(size_t)(k >> 1) * 1536 + n * 2 + (k & 1)] = f2b(src[(size_t)k * N + n]);
        }
        return;
    }
    __shared__ float tile[32][33];
#pragma unroll
    for (int i = 0; i < 32; i += 8)
        tile[ty + i][tx] = src[(size_t)(bk + ty + i) * N + bn + tx];
    __syncthreads();
#pragma unroll
    for (int i = 0; i < 32; i += 8)
        dst[(size_t)(bn + ty + i) * K + bk + tx] = f2b(tile[tx][ty + i]);
}

// ---------------- init: x = atom_emb[z], + LayerNorm(ln[0]) -> xlnb ----------------
__global__ void k_init_ln(const float* __restrict__ emb, const int* __restrict__ z,
                          const float* __restrict__ w, const float* __restrict__ b,
                          float* __restrict__ x, u16* __restrict__ xlnb) {
    int n = blockIdx.x, t = threadIdx.x;
    float v = emb[z[n] * HH + t];
    x[(size_t)n * HH + t] = v;
    float s = v, q = v * v;
#pragma unroll
    for (int m = 32; m >= 1; m >>= 1) {
        s += __shfl_xor(s, m, 64);
        q += __shfl_xor(q, m, 64);
    }
    __shared__ float s_sum[4], s_sq[4];
    int wid = t >> 6;
    if ((t & 63) == 0) { s_sum[wid] = s; s_sq[wid] = q; }
    __syncthreads();
    float S = s_sum[0] + s_sum[1] + s_sum[2] + s_sum[3];
    float Q = s_sq[0] + s_sq[1] + s_sq[2] + s_sq[3];
    float mu = S * (1.0f / HH);
    float var = Q * (1.0f / HH) - mu * mu;
    float rs = rsqrtf(var + 1e-5f);
    xlnb[(size_t)n * HH + t] = f2b((v - mu) * rs * w[t] + b[t]);
}

// ---------------- edge geometry + degree histogram (fused) ----------------
__global__ void k_geom_hist(const float* __restrict__ pos, const int* __restrict__ ei,
                            float* __restrict__ ev, int* __restrict__ deg) {
    int e = blockIdx.x * 256 + threadIdx.x;
    if (e >= EE) return;
    int s = ei[e], d = ei[EE + e];
    float rx = pos[s * 3 + 0] - pos[d * 3 + 0];
    float ry = pos[s * 3 + 1] - pos[d * 3 + 1];
    float rz = pos[s * 3 + 2] - pos[d * 3 + 2];
    float dist = sqrtf(rx * rx + ry * ry + rz * rz);
    float inv = 1.0f / dist;
    ((float4*)ev)[e] = make_float4(rx * inv, ry * inv, rz * inv, dist);
    atomicAdd(&deg[d], 1);
}

// ---------------- parallel scan: 32-block chunk scan + fixup ----------------
__global__ void k_scan1(const int* __restrict__ deg, int* __restrict__ row_ptr,
                        int* __restrict__ csum) {
    __shared__ int buf[256];
    int t = threadIdx.x, base = blockIdx.x * 256;
    int v = deg[base + t];
    buf[t] = v;
    __syncthreads();
    for (int ofs = 1; ofs < 256; ofs <<= 1) {
        int add = (t >= ofs) ? buf[t - ofs] : 0;
        __syncthreads();
        buf[t] += add;
        __syncthreads();
    }
    row_ptr[base + t] = buf[t] - v;       // chunk-local exclusive
    if (t == 255) csum[blockIdx.x] = buf[t];
}
__global__ void k_scan2(int* __restrict__ csum) {
    if (threadIdx.x == 0) {
        int acc = 0;
        for (int i = 0; i < 32; ++i) { int v = csum[i]; csum[i] = acc; acc += v; }
        csum[32] = acc;
    }
}
__global__ void k_scan3(const int* __restrict__ csum, int* __restrict__ row_ptr,
                        int* __restrict__ fill) {
    int i = blockIdx.x * 256 + threadIdx.x;
    int v = row_ptr[i] + csum[i >> 8];
    row_ptr[i] = v;
    fill[i] = v;
    if (i == 0) row_ptr[NN] = csum[32];
}

// ---------------- degree bucket-sort (descending), one block ----------------
__global__ void k_sort(const int* __restrict__ deg, int* __restrict__ dorder) {
    __shared__ int bins[256];
    __shared__ int base[256];
    int t = threadIdx.x;
    bins[t] = 0;
    __syncthreads();
    for (int d = t; d < NN; d += 256) {
        int b = deg[d]; b = b > 255 ? 255 : b;
        atomicAdd(&bins[b], 1);
    }
    __syncthreads();
    if (t == 0) {
        int acc = 0;
        for (int k = 255; k >= 0; --k) { base[k] = acc; acc += bins[k]; }
    }
    __syncthreads();
    bins[t] = 0;
    __syncthreads();
    for (int d = t; d < NN; d += 256) {
        int b = deg[d]; b = b > 255 ? 255 : b;
        int p = atomicAdd(&bins[b], 1);
        dorder[base[b] + p] = d;
    }
}

// scatter + gaussian window: 8 rows, EVEN-aligned k0; gtab packed bf16 pairs (16B)
__global__ void k_scatter(const int* __restrict__ ei, const float* __restrict__ ev,
                          int* __restrict__ fill, int* __restrict__ srcp,
                          float4* __restrict__ evp, int* __restrict__ kptab,
                          unsigned* __restrict__ gtab) {
    int e = blockIdx.x * 256 + threadIdx.x;
    if (e >= EE) return;
    int d = ei[EE + e];
    int pos = atomicAdd(&fill[d], 1);
    float4 e4 = ((const float4*)ev)[e];
    srcp[pos] = ei[e];
    evp[pos] = e4;
    const float step = 12.0f / 127.0f;
    const float coeff = -0.5f / (step * step);
    float dist = e4.w;
    int k0 = ((int)floorf(dist / step) - 3) & ~1;   // even-aligned
    k0 = k0 < 0 ? 0 : (k0 > 120 ? 120 : k0);
    float g[8];
#pragma unroll
    for (int k = 0; k < 8; ++k) {
        float t = dist - (k0 + k) * step;
        g[k] = expf(coeff * t * t);
    }
    kptab[pos] = k0 >> 1;
    unsigned g0 = (unsigned)f2b(g[0]) | ((unsigned)f2b(g[1]) << 16);
    unsigned g1 = (unsigned)f2b(g[2]) | ((unsigned)f2b(g[3]) << 16);
    unsigned g2 = (unsigned)f2b(g[4]) | ((unsigned)f2b(g[5]) << 16);
    unsigned g3 = (unsigned)f2b(g[6]) | ((unsigned)f2b(g[7]) << 16);
    ((uint4*)gtab)[pos] = make_uint4(g0, g1, g2, g3);
}

// ------ bf16 MFMA GEMM: C = act(A[M,K] @ BT[N,K]^T + bias), tile TMxTN, BK=64 ------
template <int OUT_BF16, int ACT, int TM, int TN>
__global__ __launch_bounds__(256) void k_gemm(
    const u16* __restrict__ A, const u16* __restrict__ BT,
    const float* __restrict__ bias, void* __restrict__ C, int M, int K, int N) {
    __shared__ u16 As[TM * 64];
    __shared__ u16 Bs[TN * 64];
    const int MI = TM / 32;
    const int NJ = TN / 32;
    int tid = threadIdx.x;
    int wave = tid >> 6, lane = tid & 63;
    int bm = blockIdx.y * TM, bn = blockIdx.x * TN;
    int wm = (wave & 1) * (TM / 2), wn = (wave >> 1) * (TN / 2);
    int lm = lane & 15;
    int kg = lane >> 4;
    f32x4 acc[MI][NJ] = {};

    for (int k0 = 0; k0 < K; k0 += 64) {
#pragma unroll
        for (int it = 0; it < TM / 32; ++it) {
            int idx = it * 256 + tid;
            int r = idx >> 3, seg = idx & 7;
#ifdef HAVE_GLL
            __builtin_amdgcn_global_load_lds(
                (const unsigned*)&A[(size_t)(bm + r) * K + k0 + seg * 8],
                (unsigned*)&As[idx * 8], 16, 0, 0);
#else
            *(uint4*)&As[idx * 8] = *(const uint4*)&A[(size_t)(bm + r) * K + k0 + seg * 8];
#endif
        }
#pragma unroll
        for (int it = 0; it < TN / 32; ++it) {
            int idx = it * 256 + tid;
            int r = idx >> 3, seg = idx & 7;
#ifdef HAVE_GLL
            __builtin_amdgcn_global_load_lds(
                (const unsigned*)&BT[(size_t)(bn + r) * K + k0 + seg * 8],
                (unsigned*)&Bs[idx * 8], 16, 0, 0);
#else
            *(uint4*)&Bs[idx * 8] = *(const uint4*)&BT[(size_t)(bn + r) * K + k0 + seg * 8];
#endif
        }
        __syncthreads();
#pragma unroll
        for (int kh = 0; kh < 2; ++kh) {
            bf16x8 af[MI], bfr[NJ];
#pragma unroll
            for (int i = 0; i < MI; ++i)
                af[i] = *(const bf16x8*)&As[(wm + i * 16 + lm) * 64 + kh * 32 + kg * 8];
#pragma unroll
            for (int j = 0; j < NJ; ++j)
                bfr[j] = *(const bf16x8*)&Bs[(wn + j * 16 + lm) * 64 + kh * 32 + kg * 8];
#pragma unroll
            for (int i = 0; i < MI; ++i)
#pragma unroll
                for (int j = 0; j < NJ; ++j)
                    acc[i][j] = __builtin_amdgcn_mfma_f32_16x16x32_bf16(af[i], bfr[j], acc[i][j], 0, 0, 0);
        }
        __syncthreads();
    }

#pragma unroll
    for (int j = 0; j < NJ; ++j) {
        int col = bn + wn + j * 16 + lm;
        float bv = bias ? bias[col] : 0.f;
#pragma unroll
        for (int i = 0; i < MI; ++i) {
            int row0 = bm + wm + i * 16 + kg * 4;
#pragma unroll
            for (int r = 0; r < 4; ++r) {
                float v = acc[i][j][r] + bv;
                if (ACT) v = silu(v);
                if (OUT_BF16)
                    ((u16*)C)[(size_t)(row0 + r) * N + col] = f2b(v);
                else
                    ((float*)C)[(size_t)(row0 + r) * N + col] = v;
            }
        }
    }
}

// ------ FUSED 2-stage MLP: C[M,N2] = silu(A[M,K1] @ B1T^T + b1) @ B2T^T + b2 --------
// 16-row strip per block, 4 waves. Stage-1 held in 8 KB LDS (XOR-swizzled, conflict-
// free b128 reads); B1/B2 read DIRECT from global (<=640 KB, L2-resident per XCD).
// No global intermediate, one dispatch instead of two.
template <int K1, int N2>
__global__ __launch_bounds__(256) void k_mlp2(
    const u16* __restrict__ A, const u16* __restrict__ B1T, const float* __restrict__ b1,
    const u16* __restrict__ B2T, const float* __restrict__ b2, u16* __restrict__ C) {
    __shared__ u16 Hs[16 * 256];   // 8 KB
    int tid = threadIdx.x;
    int wave = tid >> 6, lane = tid & 63;
    int lm = lane & 15, kg = lane >> 4;
    int bm = blockIdx.x * 16;
    // ---- stage 1: 16 x 256; wave computes cols [wave*64, wave*64+64) ----
    f32x4 acc1[4] = {};
    for (int kk = 0; kk < K1; kk += 32) {
        bf16x8 af = *(const bf16x8*)&A[(size_t)(bm + lm) * K1 + kk + kg * 8];
#pragma unroll
        for (int j = 0; j < 4; ++j) {
            bf16x8 bf = *(const bf16x8*)&B1T[(size_t)(wave * 64 + j * 16 + lm) * K1 + kk + kg * 8];
            acc1[j] = __builtin_amdgcn_mfma_f32_16x16x32_bf16(af, bf, acc1[j], 0, 0, 0);
        }
    }
#pragma unroll
    for (int j = 0; j < 4; ++j) {
        int col = wave * 64 + j * 16 + lm;
        float bv = b1[col];
#pragma unroll
        for (int r = 0; r < 4; ++r) {
            int row = kg * 4 + r;
            int byt = (row * 512 + col * 2) ^ ((row & 7) << 4);   // XOR swizzle
            *(u16*)((char*)Hs + byt) = f2b(silu(acc1[j][r] + bv));
        }
    }
    __syncthreads();
    // ---- stage 2: 16 x N2; wave computes cols [wave*(N2/4) ...) ----
    const int NJ = N2 / 64;
    f32x4 acc2[NJ] = {};
    int wn = wave * (N2 / 4);
    for (int kk = 0; kk < 256; kk += 32) {
        int byt = (lm * 512 + (kk + kg * 8) * 2) ^ ((lm & 7) << 4);
        bf16x8 af = *(const bf16x8*)((const char*)Hs + byt);
#pragma unroll
        for (int j = 0; j < NJ; ++j) {
            bf16x8 bf = *(const bf16x8*)&B2T[(size_t)(wn + j * 16 + lm) * 256 + kk + kg * 8];
            acc2[j] = __builtin_amdgcn_mfma_f32_16x16x32_bf16(af, bf, acc2[j], 0, 0, 0);
        }
    }
#pragma unroll
    for (int j = 0; j < NJ; ++j) {
        int col = wn + j * 16 + lm;
        float bv = b2[col];
#pragma unroll
        for (int r = 0; r < 4; ++r)
            C[(size_t)(bm + kg * 4 + r) * N2 + col] = f2b(acc2[j][r] + bv);
    }
}

// ---------------- fused message pass: node-per-wave, depth-2 edge pipeline ----------
// 512-thread blocks (8 waves): 2 independent blocks/CU (best measured variant, 98.4us).
__global__ __launch_bounds__(512) void k_msg(
    const u16* __restrict__ xhb, const u16* __restrict__ vinb,
    const int* __restrict__ srcp, const float4* __restrict__ evp,
    const int* __restrict__ row_ptr, const int* __restrict__ kptab,
    const unsigned* __restrict__ gtab, const u16* __restrict__ WP /*pair-interleaved*/,
    const float* __restrict__ rbias, float* __restrict__ x,
    const float* __restrict__ vin, u16* __restrict__ vecMb,
    const int* __restrict__ dorder) {
    __shared__ u16 Wp[64 * 512];    // 64 KB: [64 row-pairs][256 cols][2]
    int tid = threadIdx.x;
    int wave = tid >> 6, lane = tid & 63;
    int c0 = lane * 4;
    int d = dorder[blockIdx.x * MSG_WAVES + wave];
    int E0 = row_ptr[d], E1 = row_ptr[d + 1];
    float accv[3][4] = {};          // persists across panels 1,2

#pragma unroll
    for (int p = 0; p < 3; ++p) {
        __syncthreads();
#pragma unroll
        for (int it = 0; it < 8; ++it) {        // cooperative 64KB panel load
            int idx = it * 512 + tid;           // 4096 uint4
            int r = idx >> 6;                   // 64 row-pairs, 64 uint4/pair
            int c8 = (idx & 63) * 8;
            *(uint4*)&Wp[r * 512 + c8] =
                *(const uint4*)&WP[(size_t)r * 1536 + p * 512 + c8];
        }
        __syncthreads();
        float4 bb = ((const float4*)(rbias + p * 256))[lane];
        float bias4[4] = {bb.x, bb.y, bb.z, bb.w};
        float accx[4] = {};

        // ---- pipeline prologue: prefetch edge E0 ----
        int kp_n = 0; uint4 gt_n = make_uint4(0, 0, 0, 0);
        U4 X_n; U4 V0_n, V1_n, V2_n; float4 ev_n;
        X_n.v = make_ushort4(0, 0, 0, 0);
        V0_n = X_n; V1_n = X_n; V2_n = X_n;
        ev_n = make_float4(0.f, 0.f, 0.f, 0.f);
        if (E0 < E1) {
            int s0 = srcp[E0];
            kp_n = kptab[E0];
            gt_n = ((const uint4*)gtab)[E0];
            X_n.v = *(const ushort4*)(xhb + (size_t)s0 * 768 + p * 256 + c0);
            if (p == 1) {
                V0_n.v = *(const ushort4*)(vinb + (size_t)s0 * 768 + c0);
                V1_n.v = *(const ushort4*)(vinb + (size_t)s0 * 768 + 256 + c0);
                V2_n.v = *(const ushort4*)(vinb + (size_t)s0 * 768 + 512 + c0);
            }
            if (p == 2) ev_n = evp[E0];
        }
        for (int j = E0; j < E1; ++j) {
            int kp = kp_n;
            uint4 gt = gt_n;
            U4 X = X_n, V0 = V0_n, V1 = V1_n, V2 = V2_n;
            float4 ev4 = ev_n;
            if (j + 1 < E1) {
                int s2 = srcp[j + 1];
                kp_n = kptab[j + 1];
                gt_n = ((const uint4*)gtab)[j + 1];
                X_n.v = *(const ushort4*)(xhb + (size_t)s2 * 768 + p * 256 + c0);
                if (p == 1) {
                    V0_n.v = *(const ushort4*)(vinb + (size_t)s2 * 768 + c0);
                    V1_n.v = *(const ushort4*)(vinb + (size_t)s2 * 768 + 256 + c0);
                    V2_n.v = *(const ushort4*)(vinb + (size_t)s2 * 768 + 512 + c0);
                }
                if (p == 2) ev_n = evp[j + 1];
            }
            unsigned gp0 = gt.x, gp1 = gt.y, gp2 = gt.z, gp3 = gt.w;
            float rr[4] = {bias4[0], bias4[1], bias4[2], bias4[3]};
            {
                U8 w0, w1, w2, w3;
                w0.v = *(const uint4*)&Wp[(kp + 0) * 512 + c0 * 2];
                w1.v = *(const uint4*)&Wp[(kp + 1) * 512 + c0 * 2];
                w2.v = *(const uint4*)&Wp[(kp + 2) * 512 + c0 * 2];
                w3.v = *(const uint4*)&Wp[(kp + 3) * 512 + c0 * 2];
#ifdef HAVE_FDOT2
                BU g0; g0.u = gp0; BU g1; g1.u = gp1;
                BU g2; g2.u = gp2; BU g3; g3.u = gp3;
#pragma unroll
                for (int c = 0; c < 4; ++c) {
                    BU a; a.u = w0.w[c];
                    rr[c] = __builtin_amdgcn_fdot2_f32_bf16(a.v, g0.v, rr[c], false);
                    a.u = w1.w[c];
                    rr[c] = __builtin_amdgcn_fdot2_f32_bf16(a.v, g1.v, rr[c], false);
                    a.u = w2.w[c];
                    rr[c] = __builtin_amdgcn_fdot2_f32_bf16(a.v, g2.v, rr[c], false);
                    a.u = w3.w[c];
                    rr[c] = __builtin_amdgcn_fdot2_f32_bf16(a.v, g3.v, rr[c], false);
                }
#else
                float ge0 = b2f((u16)(gp0 & 0xffff)), go0 = b2f((u16)(gp0 >> 16));
                float ge1 = b2f((u16)(gp1 & 0xffff)), go1 = b2f((u16)(gp1 >> 16));
                float ge2 = b2f((u16)(gp2 & 0xffff)), go2 = b2f((u16)(gp2 >> 16));
                float ge3 = b2f((u16)(gp3 & 0xffff)), go3 = b2f((u16)(gp3 >> 16));
#pragma unroll
                for (int c = 0; c < 4; ++c) {
                    rr[c] += ge0 * b2f(w0.a[2 * c]) + go0 * b2f(w0.a[2 * c + 1]);
                    rr[c] += ge1 * b2f(w1.a[2 * c]) + go1 * b2f(w1.a[2 * c + 1]);
                    rr[c] += ge2 * b2f(w2.a[2 * c]) + go2 * b2f(w2.a[2 * c + 1]);
                    rr[c] += ge3 * b2f(w3.a[2 * c]) + go3 * b2f(w3.a[2 * c + 1]);
                }
#endif
            }
            if (p == 0) {
#pragma unroll
                for (int c = 0; c < 4; ++c) accx[c] += b2f(X.a[c]) * rr[c];
            } else if (p == 1) {
#pragma unroll
                for (int c = 0; c < 4; ++c) {
                    float m1 = b2f(X.a[c]) * rr[c] * kInvSqrt3;
                    accv[0][c] += b2f(V0.a[c]) * m1;
                    accv[1][c] += b2f(V1.a[c]) * m1;
                    accv[2][c] += b2f(V2.a[c]) * m1;
                }
            } else {
#pragma unroll
                for (int c = 0; c < 4; ++c) {
                    float m2 = b2f(X.a[c]) * rr[c];
                    accv[0][c] += m2 * ev4.x;
                    accv[1][c] += m2 * ev4.y;
                    accv[2][c] += m2 * ev4.z;
                }
            }
        }
        if (p == 0) {
            size_t xi = (size_t)d * 256 + c0;
            float4 xv = *(const float4*)&x[xi];
            xv.x = (xv.x + accx[0]) * kInvSqrt2;
            xv.y = (xv.y + accx[1]) * kInvSqrt2;
            xv.z = (xv.z + accx[2]) * kInvSqrt2;
            xv.w = (xv.w + accx[3]) * kInvSqrt2;
            *(float4*)&x[xi] = xv;
        }
    }
    // epilogue: vecM(bf16) = vin + dvec * invSqrtH
#pragma unroll
    for (int k = 0; k < 3; ++k) {
        size_t idx = (size_t)d * 768 + k * 256 + c0;
        float4 vv = *(const float4*)&vin[idx];
        ushort4 u;
        u.x = f2b(vv.x + accv[k][0] * kInvSqrtH);
        u.y = f2b(vv.y + accv[k][1] * kInvSqrtH);
        u.z = f2b(vv.z + accv[k][2] * kInvSqrtH);
        u.w = f2b(vv.w + accv[k][3] * kInvSqrtH);
        *(ushort4*)&vecMb[idx] = u;
    }
}

// ---- vec_dot + hcat: VECTORIZED (8 channels/lane, 32 lanes/node, no LDS) ----------
__global__ void k_vecdot(const u16* __restrict__ vp, const float* __restrict__ x,
                         float* __restrict__ vec_dot, u16* __restrict__ hcat) {
    int idx = blockIdx.x * 256 + threadIdx.x;   // NN*32 threads total
    int n = idx >> 5, lg = idx & 31;
    int c0 = lg * 8;
    const u16* p = vp + (size_t)n * 1536;
    float ds[8] = {}, qs[8] = {};
#pragma unroll
    for (int k = 0; k < 3; ++k) {
        uint4 a = *(const uint4*)&p[k * 512 + c0];
        uint4 b = *(const uint4*)&p[k * 512 + 256 + c0];
        const unsigned* aw = (const unsigned*)&a;
        const unsigned* bw = (const unsigned*)&b;
#pragma unroll
        for (int w = 0; w < 4; ++w) {
            float a0 = __uint_as_float(aw[w] << 16);
            float a1 = __uint_as_float(aw[w] & 0xffff0000u);
            float b0 = __uint_as_float(bw[w] << 16);
            float b1 = __uint_as_float(bw[w] & 0xffff0000u);
            ds[2 * w]     += a0 * b0;  qs[2 * w]     += b0 * b0;
            ds[2 * w + 1] += a1 * b1;  qs[2 * w + 1] += b1 * b1;
        }
    }
    size_t vo = (size_t)n * 256 + c0;
    *(float4*)&vec_dot[vo] =
        make_float4(ds[0] * kInvSqrtH, ds[1] * kInvSqrtH, ds[2] * kInvSqrtH, ds[3] * kInvSqrtH);
    *(float4*)&vec_dot[vo + 4] =
        make_float4(ds[4] * kInvSqrtH, ds[5] * kInvSqrtH, ds[6] * kInvSqrtH, ds[7] * kInvSqrtH);
    float4 x0 = *(const float4*)&x[vo];
    float4 x1 = *(const float4*)&x[vo + 4];
    *(ushort4*)&hcat[(size_t)n * 512 + c0] =
        make_ushort4(f2b(x0.x), f2b(x0.y), f2b(x0.z), f2b(x0.w));
    *(ushort4*)&hcat[(size_t)n * 512 + c0 + 4] =
        make_ushort4(f2b(x1.x), f2b(x1.y), f2b(x1.z), f2b(x1.w));
    *(ushort4*)&hcat[(size_t)n * 512 + 256 + c0] =
        make_ushort4(f2b(sqrtf(qs[0] + 1e-8f)), f2b(sqrtf(qs[1] + 1e-8f)),
                     f2b(sqrtf(qs[2] + 1e-8f)), f2b(sqrtf(qs[3] + 1e-8f)));
    *(ushort4*)&hcat[(size_t)n * 512 + 256 + c0 + 4] =
        make_ushort4(f2b(sqrtf(qs[4] + 1e-8f)), f2b(sqrtf(qs[5] + 1e-8f)),
                     f2b(sqrtf(qs[6] + 1e-8f)), f2b(sqrtf(qs[7] + 1e-8f)));
}

// ---- update epilogue + fused LayerNorm: VECTORIZED (8 ch/lane, width-32 shuffles) --
__global__ void k_update_out(const u16* __restrict__ hout, const float* __restrict__ vec_dot,
                             const u16* __restrict__ vp, float* __restrict__ x,
                             const u16* __restrict__ vecMb, float* __restrict__ vfin,
                             u16* __restrict__ vb,
                             const float* __restrict__ lnw, const float* __restrict__ lnb,
                             u16* __restrict__ xout) {
    int idx = blockIdx.x * 256 + threadIdx.x;   // NN*32 threads total
    int n = idx >> 5, lg = idx & 31;
    int c0 = lg * 8;
    size_t hb = (size_t)n * 768;
    uint4 H1 = *(const uint4*)&hout[hb + c0];
    uint4 H2 = *(const uint4*)&hout[hb + 256 + c0];
    uint4 H3 = *(const uint4*)&hout[hb + 512 + c0];
    const unsigned* h1w = (const unsigned*)&H1;
    const unsigned* h2w = (const unsigned*)&H2;
    const unsigned* h3w = (const unsigned*)&H3;
    size_t xo = (size_t)n * 256 + c0;
    float4 vd0 = *(const float4*)&vec_dot[xo];
    float4 vd1 = *(const float4*)&vec_dot[xo + 4];
    float vd[8] = {vd0.x, vd0.y, vd0.z, vd0.w, vd1.x, vd1.y, vd1.z, vd1.w};
    float4 x0 = *(const float4*)&x[xo];
    float4 x1 = *(const float4*)&x[xo + 4];
    float xv[8] = {x0.x, x0.y, x0.z, x0.w, x1.x, x1.y, x1.z, x1.w};
    float nx[8], xv3[8];
#pragma unroll
    for (int w = 0; w < 4; ++w) {
        float a1 = __uint_as_float(h1w[w] << 16), b1 = __uint_as_float(h1w[w] & 0xffff0000u);
        float a2 = __uint_as_float(h2w[w] << 16), b2v = __uint_as_float(h2w[w] & 0xffff0000u);
        nx[2 * w]     = (xv[2 * w]     + (a1 + a2  * vd[2 * w])     * kInvSqrt2) * kInvSqrt2;
        nx[2 * w + 1] = (xv[2 * w + 1] + (b1 + b2v * vd[2 * w + 1]) * kInvSqrt2) * kInvSqrt2;
        xv3[2 * w]     = __uint_as_float(h3w[w] << 16);
        xv3[2 * w + 1] = __uint_as_float(h3w[w] & 0xffff0000u);
    }
    *(float4*)&x[xo]     = make_float4(nx[0], nx[1], nx[2], nx[3]);
    *(float4*)&x[xo + 4] = make_float4(nx[4], nx[5], nx[6], nx[7]);
#pragma unroll
    for (int k = 0; k < 3; ++k) {
        size_t vo = hb + k * 256 + c0;
        uint4 VM = *(const uint4*)&vecMb[vo];
        uint4 VP = *(const uint4*)&vp[(size_t)n * 1536 + k * 512 + c0];
        const unsigned* vmw = (const unsigned*)&VM;
        const unsigned* vpw = (const unsigned*)&VP;
        float nv[8];
#pragma unroll
        for (int w = 0; w < 4; ++w) {
            nv[2 * w]     = __uint_as_float(vmw[w] << 16)
                          + xv3[2 * w]     * __uint_as_float(vpw[w] << 16);
            nv[2 * w + 1] = __uint_as_float(vmw[w] & 0xffff0000u)
                          + xv3[2 * w + 1] * __uint_as_float(vpw[w] & 0xffff0000u);
        }
        *(float4*)&vfin[vo]     = make_float4(nv[0], nv[1], nv[2], nv[3]);
        *(float4*)&vfin[vo + 4] = make_float4(nv[4], nv[5], nv[6], nv[7]);
        *(ushort4*)&vb[vo]     = make_ushort4(f2b(nv[0]), f2b(nv[1]), f2b(nv[2]), f2b(nv[3]));
        *(ushort4*)&vb[vo + 4] = make_ushort4(f2b(nv[4]), f2b(nv[5]), f2b(nv[6]), f2b(nv[7]));
    }
    if (lnw) {
        float s = 0.f, q = 0.f;
#pragma unroll
        for (int c = 0; c < 8; ++c) { s += nx[c]; q += nx[c] * nx[c]; }
#pragma unroll
        for (int m = 16; m >= 1; m >>= 1) {   // width-32: stays inside the node's group
            s += __shfl_xor(s, m, 64);
            q += __shfl_xor(q, m, 64);
        }
        float mu = s * (1.0f / HH);
        float var = q * (1.0f / HH) - mu * mu;
        float rs = rsqrtf(var + 1e-5f);
        float4 w0 = *(const float4*)&lnw[c0], w1 = *(const float4*)&lnw[c0 + 4];
        float4 bb0 = *(const float4*)&lnb[c0], bb1 = *(const float4*)&lnb[c0 + 4];
        float lw[8] = {w0.x, w0.y, w0.z, w0.w, w1.x, w1.y, w1.z, w1.w};
        float lb[8] = {bb0.x, bb0.y, bb0.z, bb0.w, bb1.x, bb1.y, bb1.z, bb1.w};
        u16 o[8];
#pragma unroll
        for (int c = 0; c < 8; ++c) o[c] = f2b((nx[c] - mu) * rs * lw[c] + lb[c]);
        *(ushort4*)&xout[xo]     = make_ushort4(o[0], o[1], o[2], o[3]);
        *(ushort4*)&xout[xo + 4] = make_ushort4(o[4], o[5], o[6], o[7]);
    } else {
        *(ushort4*)&xout[xo]     = make_ushort4(f2b(nx[0]), f2b(nx[1]), f2b(nx[2]), f2b(nx[3]));
        *(ushort4*)&xout[xo + 4] = make_ushort4(f2b(nx[4]), f2b(nx[5]), f2b(nx[6]), f2b(nx[7]));
    }
}

// ---------------- energy reduce ----------------
__global__ void k_energy2(const float* __restrict__ h, const float* __restrict__ w2,
                          const float* __restrict__ b2, const int* __restrict__ batch,
                          float* __restrict__ out) {
    __shared__ float g[NGG];
    int t = threadIdx.x;
    if (t < NGG) g[t] = 0.f;
    __syncthreads();
    int a = blockIdx.x * 256 + t;
    const float4* hr = (const float4*)(h + (size_t)a * 128);
    const float4* w4 = (const float4*)w2;
    float acc = 0.f;
#pragma unroll 8
    for (int i = 0; i < 32; ++i) {
        float4 hv = hr[i], wv = w4[i];
        acc += hv.x * wv.x + hv.y * wv.y + hv.z * wv.z + hv.w * wv.w;
    }
    acc += b2[0];
    atomicAdd(&g[batch[a]], acc);
    __syncthreads();
    if (t < NGG && g[t] != 0.f) atomicAdd(&out[t], g[t]);
}

extern "C" void kernel_launch(void* const* d_in, const int* in_sizes, int n_in,
                              void* d_out, int out_size, void* d_ws, size_t ws_size,
                              hipStream_t stream) {
    const float* pos      = (const float*)d_in[0];
    const float* atom_emb = (const float*)d_in[1];
    const float* ln_w     = (const float*)d_in[2];
    const float* ln_b     = (const float*)d_in[3];
    const float* xp_w1    = (const float*)d_in[4];
    const float* xp_b1    = (const float*)d_in[5];
    const float* xp_w2    = (const float*)d_in[6];
    const float* xp_b2    = (const float*)d_in[7];
    const float* rbf_w    = (const float*)d_in[8];
    const float* rbf_b    = (const float*)d_in[9];
    const float* vec_w    = (const float*)d_in[10];
    const float* xv_w1    = (const float*)d_in[11];
    const float* xv_b1    = (const float*)d_in[12];
    const float* xv_w2    = (const float*)d_in[13];
    const float* xv_b2    = (const float*)d_in[14];
    const float* oe_w1    = (const float*)d_in[15];
    const float* oe_b1    = (const float*)d_in[16];
    const float* oe_w2    = (const float*)d_in[17];
    const float* oe_b2    = (const float*)d_in[18];
    const int*   z        = (const int*)d_in[19];
    const int*   ei       = (const int*)d_in[20];
    const int*   batch    = (const int*)d_in[21];
    float* out = (float*)d_out;

    char* ws = (char*)d_ws;
    size_t off = 0;
    auto alloc = [&](size_t b) {
        void* p = ws + off;
        off = (off + b + 255) & ~(size_t)255;
        return p;
    };
    float*    x      = (float*)alloc((size_t)NN * HH * 4);       //   8 MB
    float*    vecA   = (float*)alloc((size_t)NN * 768 * 4);      //  24 MB  \ adjacent:
    u16*      vb     = (u16*)alloc((size_t)NN * 768 * 2);        //  12 MB  / joint zero
    u16*      vecMb  = (u16*)alloc((size_t)NN * 768 * 2);        //  12 MB
    u16*      xlnb   = (u16*)alloc((size_t)NN * HH * 2);         //   4 MB (alias xb)
    u16*      t1b    = (u16*)alloc((size_t)NN * HH * 2);         //   4 MB (unused now)
    u16*      xhb    = (u16*)alloc((size_t)NN * 768 * 2);        //  12 MB (alias hcatb)
    float*    vdot   = (float*)alloc((size_t)NN * HH * 4);       //   8 MB (alias heng)
    u16*      vpb    = (u16*)alloc((size_t)NN * 1536 * 2);       //  24 MB
    u16*      houtb  = (u16*)alloc((size_t)NN * 768 * 2);        //  12 MB
    float*    ev     = (float*)alloc((size_t)EE * 4 * 4);        //   2 MB
    int*      deg    = (int*)alloc((size_t)NN * 4);
    int*      row_ptr= (int*)alloc((size_t)(NN + 1) * 4);
    int*      fill   = (int*)alloc((size_t)NN * 4);
    int*      dorder = (int*)alloc((size_t)NN * 4);
    int*      csum   = (int*)alloc((size_t)33 * 4);
    int*      srcp   = (int*)alloc((size_t)EE * 4);
    float4*   evp    = (float4*)alloc((size_t)EE * 16);          //   2 MB
    int*      kptab  = (int*)alloc((size_t)EE * 4);              // 0.5 MB
    unsigned* gtab   = (unsigned*)alloc((size_t)EE * 16);        //   2 MB (bf16 pairs)
    u16* xp_w1T   = (u16*)alloc((size_t)3 * 256 * 256 * 2);
    u16* xp_w2T   = (u16*)alloc((size_t)3 * 768 * 256 * 2);
    u16* rbf_wP   = (u16*)alloc((size_t)3 * 128 * 768 * 2);      // pair-interleaved bf16
    u16* vec_wT   = (u16*)alloc((size_t)3 * 512 * 256 * 2);
    u16* xv_w1T   = (u16*)alloc((size_t)3 * 256 * 512 * 2);
    u16* xv_w2T   = (u16*)alloc((size_t)3 * 768 * 256 * 2);
    u16* oe_w1T   = (u16*)alloc((size_t)128 * 256 * 2);
    (void)ws_size;
    (void)t1b;

    u16*   hcatb = xhb;
    float* heng  = vdot;
    u16*   xb    = xlnb;

    // ---- setup ----
    k_wt_all<<<2432, 256, 0, stream>>>(xp_w1, xp_w2, rbf_w, vec_w, xv_w1, xv_w2, oe_w1,
                                       xp_w1T, xp_w2T, rbf_wP, vec_wT, xv_w1T, xv_w2T, oe_w1T);
    k_zero<<<(36 * 1024 * 1024 / 16 + 255) / 256, 256, 0, stream>>>(vecA, 36 * 1024 * 1024 / 16);
    k_zero<<<8, 256, 0, stream>>>((float*)deg, NN / 4);
    k_init_ln<<<NN, 256, 0, stream>>>(atom_emb, z, ln_w, ln_b, x, xlnb);
    k_geom_hist<<<EE / 256, 256, 0, stream>>>(pos, ei, ev, deg);
    k_scan1<<<32, 256, 0, stream>>>(deg, row_ptr, csum);
    k_scan2<<<1, 64, 0, stream>>>(csum);
    k_scan3<<<32, 256, 0, stream>>>(csum, row_ptr, fill);
    k_sort<<<1, 256, 0, stream>>>(deg, dorder);
    k_scatter<<<EE / 256, 256, 0, stream>>>(ei, ev, fill, srcp, evp, kptab, gtab);

    for (int l = 0; l < LL; ++l) {
        // ---- PaiNNMessage: fused 2-stage MLP then message pass ----
        k_mlp2<256, 768><<<NN / 16, 256, 0, stream>>>(
            xlnb, xp_w1T + (size_t)l * 256 * 256, xp_b1 + l * HH,
            xp_w2T + (size_t)l * 768 * 256, xp_b2 + l * 768, xhb);
        k_msg<<<NN / MSG_WAVES, 64 * MSG_WAVES, 0, stream>>>(
            xhb, vb, srcp, evp, row_ptr, kptab, gtab,
            rbf_wP + (size_t)l * 128 * 768, rbf_b + l * 768, x, vecA, vecMb, dorder);

        // ---- PaiNNUpdate ----
        k_gemm<1, 0, 64, 128><<<dim3(4, 3 * NN / 64), 256, 0, stream>>>(
            vecMb, vec_wT + (size_t)l * 512 * 256, nullptr, vpb, 3 * NN, 256, 512);
        k_vecdot<<<NN / 8, 256, 0, stream>>>(vpb, x, vdot, hcatb);
        k_mlp2<512, 768><<<NN / 16, 256, 0, stream>>>(
            hcatb, xv_w1T + (size_t)l * 256 * 512, xv_b1 + l * HH,
            xv_w2T + (size_t)l * 768 * 256, xv_b2 + l * 768, houtb);
        bool last = (l == LL - 1);
        k_update_out<<<NN / 8, 256, 0, stream>>>(
            houtb, vdot, vpb, x, vecMb, vecA, vb,
            last ? nullptr : ln_w + (l + 1) * HH,
            last ? nullptr : ln_b + (l + 1) * HH, xlnb);
    }

    // ---- energy head ----
    k_gemm<0, 1, 32, 64><<<dim3(2, NN / 32), 256, 0, stream>>>(
        xb, oe_w1T, oe_b1, heng, NN, 256, 128);
    k_zero<<<1, 256, 0, stream>>>(out, NGG / 4);
    k_energy2<<<32, 256, 0, stream>>>(heng, oe_w2, oe_b2, batch, out);
}

// Round 12
// 708.516 us; speedup vs baseline: 1.2086x; 1.2086x over previous
//
#include <hip/hip_runtime.h>
#include <hip/hip_bf16.h>
#include <math.h>

#define NN 8192
#define EE 131072
#define HH 256
#define LL 3
#define RR 128
#define NGG 64
#define MSG_WAVES 8          // waves per k_msg block (512 threads; 2 blocks/CU)

typedef __attribute__((ext_vector_type(8))) short bf16x8;
typedef __attribute__((ext_vector_type(4))) float f32x4;
typedef unsigned short u16;

#if defined(__has_builtin)
#if __has_builtin(__builtin_amdgcn_fdot2_f32_bf16)
#define HAVE_FDOT2 1
typedef __attribute__((ext_vector_type(2))) __bf16 bf16x2_t;
union BU { unsigned u; bf16x2_t v; };
#endif
#if __has_builtin(__builtin_amdgcn_global_load_lds)
#define HAVE_GLL 1
#endif
#endif

union U4 { ushort4 v; unsigned short a[4]; };
union U8 { uint4 v; unsigned short a[8]; unsigned w[4]; };

__device__ __forceinline__ float silu(float v) { return v / (1.0f + expf(-v)); }
__device__ __forceinline__ float b2f(unsigned short u) { return __uint_as_float(((unsigned)u) << 16); }
__device__ __forceinline__ unsigned short f2b(float f) {
    unsigned u = __float_as_uint(f);
    u += 0x7fff + ((u >> 16) & 1);
    return (unsigned short)(u >> 16);
}

constexpr float kInvSqrt2 = 0.70710678118654752440f;
constexpr float kInvSqrt3 = 0.57735026918962576451f;
constexpr float kInvSqrtH = 0.0625f; // 1/sqrt(256)

// ---------------- utility ----------------
__global__ void k_zero(float* __restrict__ p, int n4) {
    int i = blockIdx.x * 256 + threadIdx.x;
    if (i < n4) ((float4*)p)[i] = make_float4(0.f, 0.f, 0.f, 0.f);
}

// ---------------- ALL weight prep in one launch ----------------
// transpose in[K,N] fp32 -> out[N,K] bf16; rbf_w: row-PAIR interleaved k-major bf16
__global__ __launch_bounds__(256) void k_wt_all(
    const float* __restrict__ xp_w1, const float* __restrict__ xp_w2,
    const float* __restrict__ rbf_w, const float* __restrict__ vec_w,
    const float* __restrict__ xv_w1, const float* __restrict__ xv_w2,
    const float* __restrict__ oe_w1,
    u16* __restrict__ xp_w1T, u16* __restrict__ xp_w2T, u16* __restrict__ rbf_wP,
    u16* __restrict__ vec_wT, u16* __restrict__ xv_w1T, u16* __restrict__ xv_w2T,
    u16* __restrict__ oe_w1T) {
    int bid = blockIdx.x;
    const float* src; u16* dst; int K, N, t, pairmode = 0;
    if (bid < 2400) {
        int l = bid / 800, r = bid % 800;
        if (r < 64)       { src = xp_w1 + (size_t)l * 65536;  dst = xp_w1T + (size_t)l * 65536;  K = 256; N = 256; t = r; }
        else if (r < 256) { src = xp_w2 + (size_t)l * 196608; dst = xp_w2T + (size_t)l * 196608; K = 256; N = 768; t = r - 64; }
        else if (r < 352) { src = rbf_w + (size_t)l * 98304;  dst = rbf_wP + (size_t)l * 98304;  K = 128; N = 768; t = r - 256; pairmode = 1; }
        else if (r < 480) { src = vec_w + (size_t)l * 131072; dst = vec_wT + (size_t)l * 131072; K = 256; N = 512; t = r - 352; }
        else if (r < 608) { src = xv_w1 + (size_t)l * 131072; dst = xv_w1T + (size_t)l * 131072; K = 512; N = 256; t = r - 480; }
        else              { src = xv_w2 + (size_t)l * 196608; dst = xv_w2T + (size_t)l * 196608; K = 256; N = 768; t = r - 608; }
    } else {
        src = oe_w1; dst = oe_w1T; K = 256; N = 128; t = bid - 2400;
    }
    int nx = N >> 5;
    int bn = (t % nx) * 32, bk = (t / nx) * 32;
    int tx = threadIdx.x & 31, ty = threadIdx.x >> 5;   // 32 x 8
    if (pairmode) {
#pragma unroll
        for (int i = 0; i < 32; i += 8) {
            int k = bk + ty + i, n = bn + tx;
            dst[(size_t)(k >> 1) * 1536 + n * 2 + (k & 1)] = f2b(src[(size_t)k * N + n]);
        }
        return;
    }
    __shared__ float tile[32][33];
#pragma unroll
    for (int i = 0; i < 32; i += 8)
        tile[ty + i][tx] = src[(size_t)(bk + ty + i) * N + bn + tx];
    __syncthreads();
#pragma unroll
    for (int i = 0; i < 32; i += 8)
        dst[(size_t)(bn + ty + i) * K + bk + tx] = f2b(tile[tx][ty + i]);
}

// ---------------- init: x = atom_emb[z], + LayerNorm(ln[0]) -> xlnb ----------------
__global__ void k_init_ln(const float* __restrict__ emb, const int* __restrict__ z,
                          const float* __restrict__ w, const float* __restrict__ b,
                          float* __restrict__ x, u16* __restrict__ xlnb) {
    int n = blockIdx.x, t = threadIdx.x;
    float v = emb[z[n] * HH + t];
    x[(size_t)n * HH + t] = v;
    float s = v, q = v * v;
#pragma unroll
    for (int m = 32; m >= 1; m >>= 1) {
        s += __shfl_xor(s, m, 64);
        q += __shfl_xor(q, m, 64);
    }
    __shared__ float s_sum[4], s_sq[4];
    int wid = t >> 6;
    if ((t & 63) == 0) { s_sum[wid] = s; s_sq[wid] = q; }
    __syncthreads();
    float S = s_sum[0] + s_sum[1] + s_sum[2] + s_sum[3];
    float Q = s_sq[0] + s_sq[1] + s_sq[2] + s_sq[3];
    float mu = S * (1.0f / HH);
    float var = Q * (1.0f / HH) - mu * mu;
    float rs = rsqrtf(var + 1e-5f);
    xlnb[(size_t)n * HH + t] = f2b((v - mu) * rs * w[t] + b[t]);
}

// ---------------- edge geometry + degree histogram (fused) ----------------
__global__ void k_geom_hist(const float* __restrict__ pos, const int* __restrict__ ei,
                            float* __restrict__ ev, int* __restrict__ deg) {
    int e = blockIdx.x * 256 + threadIdx.x;
    if (e >= EE) return;
    int s = ei[e], d = ei[EE + e];
    float rx = pos[s * 3 + 0] - pos[d * 3 + 0];
    float ry = pos[s * 3 + 1] - pos[d * 3 + 1];
    float rz = pos[s * 3 + 2] - pos[d * 3 + 2];
    float dist = sqrtf(rx * rx + ry * ry + rz * rz);
    float inv = 1.0f / dist;
    ((float4*)ev)[e] = make_float4(rx * inv, ry * inv, rz * inv, dist);
    atomicAdd(&deg[d], 1);
}

// ---------------- parallel scan: 32-block chunk scan + fixup ----------------
__global__ void k_scan1(const int* __restrict__ deg, int* __restrict__ row_ptr,
                        int* __restrict__ csum) {
    __shared__ int buf[256];
    int t = threadIdx.x, base = blockIdx.x * 256;
    int v = deg[base + t];
    buf[t] = v;
    __syncthreads();
    for (int ofs = 1; ofs < 256; ofs <<= 1) {
        int add = (t >= ofs) ? buf[t - ofs] : 0;
        __syncthreads();
        buf[t] += add;
        __syncthreads();
    }
    row_ptr[base + t] = buf[t] - v;       // chunk-local exclusive
    if (t == 255) csum[blockIdx.x] = buf[t];
}
__global__ void k_scan2(int* __restrict__ csum) {
    if (threadIdx.x == 0) {
        int acc = 0;
        for (int i = 0; i < 32; ++i) { int v = csum[i]; csum[i] = acc; acc += v; }
        csum[32] = acc;
    }
}
__global__ void k_scan3(const int* __restrict__ csum, int* __restrict__ row_ptr,
                        int* __restrict__ fill) {
    int i = blockIdx.x * 256 + threadIdx.x;
    int v = row_ptr[i] + csum[i >> 8];
    row_ptr[i] = v;
    fill[i] = v;
    if (i == 0) row_ptr[NN] = csum[32];
}

// ---------------- degree bucket-sort (descending), one block ----------------
__global__ void k_sort(const int* __restrict__ deg, int* __restrict__ dorder) {
    __shared__ int bins[256];
    __shared__ int base[256];
    int t = threadIdx.x;
    bins[t] = 0;
    __syncthreads();
    for (int d = t; d < NN; d += 256) {
        int b = deg[d]; b = b > 255 ? 255 : b;
        atomicAdd(&bins[b], 1);
    }
    __syncthreads();
    if (t == 0) {
        int acc = 0;
        for (int k = 255; k >= 0; --k) { base[k] = acc; acc += bins[k]; }
    }
    __syncthreads();
    bins[t] = 0;
    __syncthreads();
    for (int d = t; d < NN; d += 256) {
        int b = deg[d]; b = b > 255 ? 255 : b;
        int p = atomicAdd(&bins[b], 1);
        dorder[base[b] + p] = d;
    }
}

// scatter + gaussian window: 8 rows, EVEN-aligned k0; gtab packed bf16 pairs (16B)
__global__ void k_scatter(const int* __restrict__ ei, const float* __restrict__ ev,
                          int* __restrict__ fill, int* __restrict__ srcp,
                          float4* __restrict__ evp, int* __restrict__ kptab,
                          unsigned* __restrict__ gtab) {
    int e = blockIdx.x * 256 + threadIdx.x;
    if (e >= EE) return;
    int d = ei[EE + e];
    int pos = atomicAdd(&fill[d], 1);
    float4 e4 = ((const float4*)ev)[e];
    srcp[pos] = ei[e];
    evp[pos] = e4;
    const float step = 12.0f / 127.0f;
    const float coeff = -0.5f / (step * step);
    float dist = e4.w;
    int k0 = ((int)floorf(dist / step) - 3) & ~1;   // even-aligned
    k0 = k0 < 0 ? 0 : (k0 > 120 ? 120 : k0);
    float g[8];
#pragma unroll
    for (int k = 0; k < 8; ++k) {
        float t = dist - (k0 + k) * step;
        g[k] = expf(coeff * t * t);
    }
    kptab[pos] = k0 >> 1;
    unsigned g0 = (unsigned)f2b(g[0]) | ((unsigned)f2b(g[1]) << 16);
    unsigned g1 = (unsigned)f2b(g[2]) | ((unsigned)f2b(g[3]) << 16);
    unsigned g2 = (unsigned)f2b(g[4]) | ((unsigned)f2b(g[5]) << 16);
    unsigned g3 = (unsigned)f2b(g[6]) | ((unsigned)f2b(g[7]) << 16);
    ((uint4*)gtab)[pos] = make_uint4(g0, g1, g2, g3);
}

// ------ bf16 MFMA GEMM: C = act(A[M,K] @ BT[N,K]^T + bias), tile TMxTN, BK=64 ------
// TM=32 for the grid-starved shapes (doubles resident waves); TM=64 where grid >=6/CU.
template <int OUT_BF16, int ACT, int TM, int TN>
__global__ __launch_bounds__(256) void k_gemm(
    const u16* __restrict__ A, const u16* __restrict__ BT,
    const float* __restrict__ bias, void* __restrict__ C, int M, int K, int N) {
    __shared__ u16 As[TM * 64];    // TM=32: 4 KB, TM=64: 8 KB
    __shared__ u16 Bs[TN * 64];    // TN=64: 8 KB, TN=128: 16 KB
    const int MI = TM / 32;        // i-frags per wave
    const int NJ = TN / 32;        // j-frags per wave
    int tid = threadIdx.x;
    int wave = tid >> 6, lane = tid & 63;
    int bm = blockIdx.y * TM, bn = blockIdx.x * TN;
    int wm = (wave & 1) * (TM / 2), wn = (wave >> 1) * (TN / 2);
    int lm = lane & 15;
    int kg = lane >> 4;
    f32x4 acc[MI][NJ] = {};

    for (int k0 = 0; k0 < K; k0 += 64) {
#pragma unroll
        for (int it = 0; it < TM / 32; ++it) { // A: TM rows x 64k x 2B
            int idx = it * 256 + tid;
            int r = idx >> 3, seg = idx & 7;
#ifdef HAVE_GLL
            __builtin_amdgcn_global_load_lds(
                (const unsigned*)&A[(size_t)(bm + r) * K + k0 + seg * 8],
                (unsigned*)&As[idx * 8], 16, 0, 0);
#else
            *(uint4*)&As[idx * 8] = *(const uint4*)&A[(size_t)(bm + r) * K + k0 + seg * 8];
#endif
        }
#pragma unroll
        for (int it = 0; it < TN / 32; ++it) { // B: TN rows x 64k x 2B
            int idx = it * 256 + tid;
            int r = idx >> 3, seg = idx & 7;
#ifdef HAVE_GLL
            __builtin_amdgcn_global_load_lds(
                (const unsigned*)&BT[(size_t)(bn + r) * K + k0 + seg * 8],
                (unsigned*)&Bs[idx * 8], 16, 0, 0);
#else
            *(uint4*)&Bs[idx * 8] = *(const uint4*)&BT[(size_t)(bn + r) * K + k0 + seg * 8];
#endif
        }
        __syncthreads();
#pragma unroll
        for (int kh = 0; kh < 2; ++kh) {
            bf16x8 af[MI], bfr[NJ];
#pragma unroll
            for (int i = 0; i < MI; ++i)
                af[i] = *(const bf16x8*)&As[(wm + i * 16 + lm) * 64 + kh * 32 + kg * 8];
#pragma unroll
            for (int j = 0; j < NJ; ++j)
                bfr[j] = *(const bf16x8*)&Bs[(wn + j * 16 + lm) * 64 + kh * 32 + kg * 8];
#pragma unroll
            for (int i = 0; i < MI; ++i)
#pragma unroll
                for (int j = 0; j < NJ; ++j)
                    acc[i][j] = __builtin_amdgcn_mfma_f32_16x16x32_bf16(af[i], bfr[j], acc[i][j], 0, 0, 0);
        }
        __syncthreads();
    }

#pragma unroll
    for (int j = 0; j < NJ; ++j) {
        int col = bn + wn + j * 16 + lm;
        float bv = bias ? bias[col] : 0.f;
#pragma unroll
        for (int i = 0; i < MI; ++i) {
            int row0 = bm + wm + i * 16 + kg * 4;
#pragma unroll
            for (int r = 0; r < 4; ++r) {
                float v = acc[i][j][r] + bv;
                if (ACT) v = silu(v);
                if (OUT_BF16)
                    ((u16*)C)[(size_t)(row0 + r) * N + col] = f2b(v);
                else
                    ((float*)C)[(size_t)(row0 + r) * N + col] = v;
            }
        }
    }
}

// ---------------- fused message pass: node-per-wave, depth-2 edge pipeline ----------
// 512-thread blocks (8 waves): 2 independent blocks/CU (best measured variant, 98.4us).
__global__ __launch_bounds__(512) void k_msg(
    const u16* __restrict__ xhb, const u16* __restrict__ vinb,
    const int* __restrict__ srcp, const float4* __restrict__ evp,
    const int* __restrict__ row_ptr, const int* __restrict__ kptab,
    const unsigned* __restrict__ gtab, const u16* __restrict__ WP /*pair-interleaved*/,
    const float* __restrict__ rbias, float* __restrict__ x,
    const float* __restrict__ vin, u16* __restrict__ vecMb,
    const int* __restrict__ dorder) {
    __shared__ u16 Wp[64 * 512];    // 64 KB: [64 row-pairs][256 cols][2]
    int tid = threadIdx.x;
    int wave = tid >> 6, lane = tid & 63;
    int c0 = lane * 4;
    int d = dorder[blockIdx.x * MSG_WAVES + wave];
    int E0 = row_ptr[d], E1 = row_ptr[d + 1];
    float accv[3][4] = {};          // persists across panels 1,2

#pragma unroll
    for (int p = 0; p < 3; ++p) {
        __syncthreads();
#pragma unroll
        for (int it = 0; it < 8; ++it) {        // cooperative 64KB panel load
            int idx = it * 512 + tid;           // 4096 uint4
            int r = idx >> 6;                   // 64 row-pairs, 64 uint4/pair
            int c8 = (idx & 63) * 8;
            *(uint4*)&Wp[r * 512 + c8] =
                *(const uint4*)&WP[(size_t)r * 1536 + p * 512 + c8];
        }
        __syncthreads();
        float4 bb = ((const float4*)(rbias + p * 256))[lane];
        float bias4[4] = {bb.x, bb.y, bb.z, bb.w};
        float accx[4] = {};

        // ---- pipeline prologue: prefetch edge E0 ----
        int kp_n = 0; uint4 gt_n = make_uint4(0, 0, 0, 0);
        U4 X_n; U4 V0_n, V1_n, V2_n; float4 ev_n;
        X_n.v = make_ushort4(0, 0, 0, 0);
        V0_n = X_n; V1_n = X_n; V2_n = X_n;
        ev_n = make_float4(0.f, 0.f, 0.f, 0.f);
        if (E0 < E1) {
            int s0 = srcp[E0];
            kp_n = kptab[E0];
            gt_n = ((const uint4*)gtab)[E0];
            X_n.v = *(const ushort4*)(xhb + (size_t)s0 * 768 + p * 256 + c0);
            if (p == 1) {
                V0_n.v = *(const ushort4*)(vinb + (size_t)s0 * 768 + c0);
                V1_n.v = *(const ushort4*)(vinb + (size_t)s0 * 768 + 256 + c0);
                V2_n.v = *(const ushort4*)(vinb + (size_t)s0 * 768 + 512 + c0);
            }
            if (p == 2) ev_n = evp[E0];
        }
        for (int j = E0; j < E1; ++j) {
            int kp = kp_n;
            uint4 gt = gt_n;
            U4 X = X_n, V0 = V0_n, V1 = V1_n, V2 = V2_n;
            float4 ev4 = ev_n;
            if (j + 1 < E1) {
                int s2 = srcp[j + 1];
                kp_n = kptab[j + 1];
                gt_n = ((const uint4*)gtab)[j + 1];
                X_n.v = *(const ushort4*)(xhb + (size_t)s2 * 768 + p * 256 + c0);
                if (p == 1) {
                    V0_n.v = *(const ushort4*)(vinb + (size_t)s2 * 768 + c0);
                    V1_n.v = *(const ushort4*)(vinb + (size_t)s2 * 768 + 256 + c0);
                    V2_n.v = *(const ushort4*)(vinb + (size_t)s2 * 768 + 512 + c0);
                }
                if (p == 2) ev_n = evp[j + 1];
            }
            unsigned gp0 = gt.x, gp1 = gt.y, gp2 = gt.z, gp3 = gt.w;
            float rr[4] = {bias4[0], bias4[1], bias4[2], bias4[3]};
            {
                U8 w0, w1, w2, w3;
                w0.v = *(const uint4*)&Wp[(kp + 0) * 512 + c0 * 2];
                w1.v = *(const uint4*)&Wp[(kp + 1) * 512 + c0 * 2];
                w2.v = *(const uint4*)&Wp[(kp + 2) * 512 + c0 * 2];
                w3.v = *(const uint4*)&Wp[(kp + 3) * 512 + c0 * 2];
#ifdef HAVE_FDOT2
                BU g0; g0.u = gp0; BU g1; g1.u = gp1;
                BU g2; g2.u = gp2; BU g3; g3.u = gp3;
#pragma unroll
                for (int c = 0; c < 4; ++c) {
                    BU a; a.u = w0.w[c];
                    rr[c] = __builtin_amdgcn_fdot2_f32_bf16(a.v, g0.v, rr[c], false);
                    a.u = w1.w[c];
                    rr[c] = __builtin_amdgcn_fdot2_f32_bf16(a.v, g1.v, rr[c], false);
                    a.u = w2.w[c];
                    rr[c] = __builtin_amdgcn_fdot2_f32_bf16(a.v, g2.v, rr[c], false);
                    a.u = w3.w[c];
                    rr[c] = __builtin_amdgcn_fdot2_f32_bf16(a.v, g3.v, rr[c], false);
                }
#else
                float ge0 = b2f((u16)(gp0 & 0xffff)), go0 = b2f((u16)(gp0 >> 16));
                float ge1 = b2f((u16)(gp1 & 0xffff)), go1 = b2f((u16)(gp1 >> 16));
                float ge2 = b2f((u16)(gp2 & 0xffff)), go2 = b2f((u16)(gp2 >> 16));
                float ge3 = b2f((u16)(gp3 & 0xffff)), go3 = b2f((u16)(gp3 >> 16));
#pragma unroll
                for (int c = 0; c < 4; ++c) {
                    rr[c] += ge0 * b2f(w0.a[2 * c]) + go0 * b2f(w0.a[2 * c + 1]);
                    rr[c] += ge1 * b2f(w1.a[2 * c]) + go1 * b2f(w1.a[2 * c + 1]);
                    rr[c] += ge2 * b2f(w2.a[2 * c]) + go2 * b2f(w2.a[2 * c + 1]);
                    rr[c] += ge3 * b2f(w3.a[2 * c]) + go3 * b2f(w3.a[2 * c + 1]);
                }
#endif
            }
            if (p == 0) {
#pragma unroll
                for (int c = 0; c < 4; ++c) accx[c] += b2f(X.a[c]) * rr[c];
            } else if (p == 1) {
#pragma unroll
                for (int c = 0; c < 4; ++c) {
                    float m1 = b2f(X.a[c]) * rr[c] * kInvSqrt3;
                    accv[0][c] += b2f(V0.a[c]) * m1;
                    accv[1][c] += b2f(V1.a[c]) * m1;
                    accv[2][c] += b2f(V2.a[c]) * m1;
                }
            } else {
#pragma unroll
                for (int c = 0; c < 4; ++c) {
                    float m2 = b2f(X.a[c]) * rr[c];
                    accv[0][c] += m2 * ev4.x;
                    accv[1][c] += m2 * ev4.y;
                    accv[2][c] += m2 * ev4.z;
                }
            }
        }
        if (p == 0) {
            size_t xi = (size_t)d * 256 + c0;
            float4 xv = *(const float4*)&x[xi];
            xv.x = (xv.x + accx[0]) * kInvSqrt2;
            xv.y = (xv.y + accx[1]) * kInvSqrt2;
            xv.z = (xv.z + accx[2]) * kInvSqrt2;
            xv.w = (xv.w + accx[3]) * kInvSqrt2;
            *(float4*)&x[xi] = xv;
        }
    }
    // epilogue: vecM(bf16) = vin + dvec * invSqrtH
#pragma unroll
    for (int k = 0; k < 3; ++k) {
        size_t idx = (size_t)d * 768 + k * 256 + c0;
        float4 vv = *(const float4*)&vin[idx];
        ushort4 u;
        u.x = f2b(vv.x + accv[k][0] * kInvSqrtH);
        u.y = f2b(vv.y + accv[k][1] * kInvSqrtH);
        u.z = f2b(vv.z + accv[k][2] * kInvSqrtH);
        u.w = f2b(vv.w + accv[k][3] * kInvSqrtH);
        *(ushort4*)&vecMb[idx] = u;
    }
}

// ---- vec_dot + hcat: VECTORIZED (8 channels/lane, 32 lanes/node, no LDS) ----------
__global__ void k_vecdot(const u16* __restrict__ vp, const float* __restrict__ x,
                         float* __restrict__ vec_dot, u16* __restrict__ hcat) {
    int idx = blockIdx.x * 256 + threadIdx.x;   // NN*32 threads total
    int n = idx >> 5, lg = idx & 31;
    int c0 = lg * 8;
    const u16* p = vp + (size_t)n * 1536;
    float ds[8] = {}, qs[8] = {};
#pragma unroll
    for (int k = 0; k < 3; ++k) {
        uint4 a = *(const uint4*)&p[k * 512 + c0];
        uint4 b = *(const uint4*)&p[k * 512 + 256 + c0];
        const unsigned* aw = (const unsigned*)&a;
        const unsigned* bw = (const unsigned*)&b;
#pragma unroll
        for (int w = 0; w < 4; ++w) {
            float a0 = __uint_as_float(aw[w] << 16);
            float a1 = __uint_as_float(aw[w] & 0xffff0000u);
            float b0 = __uint_as_float(bw[w] << 16);
            float b1 = __uint_as_float(bw[w] & 0xffff0000u);
            ds[2 * w]     += a0 * b0;  qs[2 * w]     += b0 * b0;
            ds[2 * w + 1] += a1 * b1;  qs[2 * w + 1] += b1 * b1;
        }
    }
    size_t vo = (size_t)n * 256 + c0;
    *(float4*)&vec_dot[vo] =
        make_float4(ds[0] * kInvSqrtH, ds[1] * kInvSqrtH, ds[2] * kInvSqrtH, ds[3] * kInvSqrtH);
    *(float4*)&vec_dot[vo + 4] =
        make_float4(ds[4] * kInvSqrtH, ds[5] * kInvSqrtH, ds[6] * kInvSqrtH, ds[7] * kInvSqrtH);
    float4 x0 = *(const float4*)&x[vo];
    float4 x1 = *(const float4*)&x[vo + 4];
    *(ushort4*)&hcat[(size_t)n * 512 + c0] =
        make_ushort4(f2b(x0.x), f2b(x0.y), f2b(x0.z), f2b(x0.w));
    *(ushort4*)&hcat[(size_t)n * 512 + c0 + 4] =
        make_ushort4(f2b(x1.x), f2b(x1.y), f2b(x1.z), f2b(x1.w));
    *(ushort4*)&hcat[(size_t)n * 512 + 256 + c0] =
        make_ushort4(f2b(sqrtf(qs[0] + 1e-8f)), f2b(sqrtf(qs[1] + 1e-8f)),
                     f2b(sqrtf(qs[2] + 1e-8f)), f2b(sqrtf(qs[3] + 1e-8f)));
    *(ushort4*)&hcat[(size_t)n * 512 + 256 + c0 + 4] =
        make_ushort4(f2b(sqrtf(qs[4] + 1e-8f)), f2b(sqrtf(qs[5] + 1e-8f)),
                     f2b(sqrtf(qs[6] + 1e-8f)), f2b(sqrtf(qs[7] + 1e-8f)));
}

// ---- update epilogue + fused LayerNorm: VECTORIZED (8 ch/lane, width-32 shuffles) --
__global__ void k_update_out(const u16* __restrict__ hout, const float* __restrict__ vec_dot,
                             const u16* __restrict__ vp, float* __restrict__ x,
                             const u16* __restrict__ vecMb, float* __restrict__ vfin,
                             u16* __restrict__ vb,
                             const float* __restrict__ lnw, const float* __restrict__ lnb,
                             u16* __restrict__ xout) {
    int idx = blockIdx.x * 256 + threadIdx.x;   // NN*32 threads total
    int n = idx >> 5, lg = idx & 31;
    int c0 = lg * 8;
    size_t hb = (size_t)n * 768;
    uint4 H1 = *(const uint4*)&hout[hb + c0];
    uint4 H2 = *(const uint4*)&hout[hb + 256 + c0];
    uint4 H3 = *(const uint4*)&hout[hb + 512 + c0];
    const unsigned* h1w = (const unsigned*)&H1;
    const unsigned* h2w = (const unsigned*)&H2;
    const unsigned* h3w = (const unsigned*)&H3;
    size_t xo = (size_t)n * 256 + c0;
    float4 vd0 = *(const float4*)&vec_dot[xo];
    float4 vd1 = *(const float4*)&vec_dot[xo + 4];
    float vd[8] = {vd0.x, vd0.y, vd0.z, vd0.w, vd1.x, vd1.y, vd1.z, vd1.w};
    float4 x0 = *(const float4*)&x[xo];
    float4 x1 = *(const float4*)&x[xo + 4];
    float xv[8] = {x0.x, x0.y, x0.z, x0.w, x1.x, x1.y, x1.z, x1.w};
    float nx[8], xv3[8];
#pragma unroll
    for (int w = 0; w < 4; ++w) {
        float a1 = __uint_as_float(h1w[w] << 16), b1 = __uint_as_float(h1w[w] & 0xffff0000u);
        float a2 = __uint_as_float(h2w[w] << 16), b2v = __uint_as_float(h2w[w] & 0xffff0000u);
        nx[2 * w]     = (xv[2 * w]     + (a1 + a2  * vd[2 * w])     * kInvSqrt2) * kInvSqrt2;
        nx[2 * w + 1] = (xv[2 * w + 1] + (b1 + b2v * vd[2 * w + 1]) * kInvSqrt2) * kInvSqrt2;
        xv3[2 * w]     = __uint_as_float(h3w[w] << 16);
        xv3[2 * w + 1] = __uint_as_float(h3w[w] & 0xffff0000u);
    }
    *(float4*)&x[xo]     = make_float4(nx[0], nx[1], nx[2], nx[3]);
    *(float4*)&x[xo + 4] = make_float4(nx[4], nx[5], nx[6], nx[7]);
#pragma unroll
    for (int k = 0; k < 3; ++k) {
        size_t vo = hb + k * 256 + c0;
        uint4 VM = *(const uint4*)&vecMb[vo];
        uint4 VP = *(const uint4*)&vp[(size_t)n * 1536 + k * 512 + c0];
        const unsigned* vmw = (const unsigned*)&VM;
        const unsigned* vpw = (const unsigned*)&VP;
        float nv[8];
#pragma unroll
        for (int w = 0; w < 4; ++w) {
            nv[2 * w]     = __uint_as_float(vmw[w] << 16)
                          + xv3[2 * w]     * __uint_as_float(vpw[w] << 16);
            nv[2 * w + 1] = __uint_as_float(vmw[w] & 0xffff0000u)
                          + xv3[2 * w + 1] * __uint_as_float(vpw[w] & 0xffff0000u);
        }
        *(float4*)&vfin[vo]     = make_float4(nv[0], nv[1], nv[2], nv[3]);
        *(float4*)&vfin[vo + 4] = make_float4(nv[4], nv[5], nv[6], nv[7]);
        *(ushort4*)&vb[vo]     = make_ushort4(f2b(nv[0]), f2b(nv[1]), f2b(nv[2]), f2b(nv[3]));
        *(ushort4*)&vb[vo + 4] = make_ushort4(f2b(nv[4]), f2b(nv[5]), f2b(nv[6]), f2b(nv[7]));
    }
    if (lnw) {
        float s = 0.f, q = 0.f;
#pragma unroll
        for (int c = 0; c < 8; ++c) { s += nx[c]; q += nx[c] * nx[c]; }
#pragma unroll
        for (int m = 16; m >= 1; m >>= 1) {   // width-32: stays inside the node's group
            s += __shfl_xor(s, m, 64);
            q += __shfl_xor(q, m, 64);
        }
        float mu = s * (1.0f / HH);
        float var = q * (1.0f / HH) - mu * mu;
        float rs = rsqrtf(var + 1e-5f);
        float4 w0 = *(const float4*)&lnw[c0], w1 = *(const float4*)&lnw[c0 + 4];
        float4 bb0 = *(const float4*)&lnb[c0], bb1 = *(const float4*)&lnb[c0 + 4];
        float lw[8] = {w0.x, w0.y, w0.z, w0.w, w1.x, w1.y, w1.z, w1.w};
        float lb[8] = {bb0.x, bb0.y, bb0.z, bb0.w, bb1.x, bb1.y, bb1.z, bb1.w};
        u16 o[8];
#pragma unroll
        for (int c = 0; c < 8; ++c) o[c] = f2b((nx[c] - mu) * rs * lw[c] + lb[c]);
        *(ushort4*)&xout[xo]     = make_ushort4(o[0], o[1], o[2], o[3]);
        *(ushort4*)&xout[xo + 4] = make_ushort4(o[4], o[5], o[6], o[7]);
    } else {
        *(ushort4*)&xout[xo]     = make_ushort4(f2b(nx[0]), f2b(nx[1]), f2b(nx[2]), f2b(nx[3]));
        *(ushort4*)&xout[xo + 4] = make_ushort4(f2b(nx[4]), f2b(nx[5]), f2b(nx[6]), f2b(nx[7]));
    }
}

// ---------------- energy reduce ----------------
__global__ void k_energy2(const float* __restrict__ h, const float* __restrict__ w2,
                          const float* __restrict__ b2, const int* __restrict__ batch,
                          float* __restrict__ out) {
    __shared__ float g[NGG];
    int t = threadIdx.x;
    if (t < NGG) g[t] = 0.f;
    __syncthreads();
    int a = blockIdx.x * 256 + t;
    const float4* hr = (const float4*)(h + (size_t)a * 128);
    const float4* w4 = (const float4*)w2;
    float acc = 0.f;
#pragma unroll 8
    for (int i = 0; i < 32; ++i) {
        float4 hv = hr[i], wv = w4[i];
        acc += hv.x * wv.x + hv.y * wv.y + hv.z * wv.z + hv.w * wv.w;
    }
    acc += b2[0];
    atomicAdd(&g[batch[a]], acc);
    __syncthreads();
    if (t < NGG && g[t] != 0.f) atomicAdd(&out[t], g[t]);
}

extern "C" void kernel_launch(void* const* d_in, const int* in_sizes, int n_in,
                              void* d_out, int out_size, void* d_ws, size_t ws_size,
                              hipStream_t stream) {
    const float* pos      = (const float*)d_in[0];
    const float* atom_emb = (const float*)d_in[1];
    const float* ln_w     = (const float*)d_in[2];
    const float* ln_b     = (const float*)d_in[3];
    const float* xp_w1    = (const float*)d_in[4];
    const float* xp_b1    = (const float*)d_in[5];
    const float* xp_w2    = (const float*)d_in[6];
    const float* xp_b2    = (const float*)d_in[7];
    const float* rbf_w    = (const float*)d_in[8];
    const float* rbf_b    = (const float*)d_in[9];
    const float* vec_w    = (const float*)d_in[10];
    const float* xv_w1    = (const float*)d_in[11];
    const float* xv_b1    = (const float*)d_in[12];
    const float* xv_w2    = (const float*)d_in[13];
    const float* xv_b2    = (const float*)d_in[14];
    const float* oe_w1    = (const float*)d_in[15];
    const float* oe_b1    = (const float*)d_in[16];
    const float* oe_w2    = (const float*)d_in[17];
    const float* oe_b2    = (const float*)d_in[18];
    const int*   z        = (const int*)d_in[19];
    const int*   ei       = (const int*)d_in[20];
    const int*   batch    = (const int*)d_in[21];
    float* out = (float*)d_out;

    char* ws = (char*)d_ws;
    size_t off = 0;
    auto alloc = [&](size_t b) {
        void* p = ws + off;
        off = (off + b + 255) & ~(size_t)255;
        return p;
    };
    float*    x      = (float*)alloc((size_t)NN * HH * 4);       //   8 MB
    float*    vecA   = (float*)alloc((size_t)NN * 768 * 4);      //  24 MB  \ adjacent:
    u16*      vb     = (u16*)alloc((size_t)NN * 768 * 2);        //  12 MB  / joint zero
    u16*      vecMb  = (u16*)alloc((size_t)NN * 768 * 2);        //  12 MB
    u16*      xlnb   = (u16*)alloc((size_t)NN * HH * 2);         //   4 MB (alias xb)
    u16*      t1b    = (u16*)alloc((size_t)NN * HH * 2);         //   4 MB (alias h1b)
    u16*      xhb    = (u16*)alloc((size_t)NN * 768 * 2);        //  12 MB (alias hcatb)
    float*    vdot   = (float*)alloc((size_t)NN * HH * 4);       //   8 MB (alias heng)
    u16*      vpb    = (u16*)alloc((size_t)NN * 1536 * 2);       //  24 MB
    u16*      houtb  = (u16*)alloc((size_t)NN * 768 * 2);        //  12 MB
    float*    ev     = (float*)alloc((size_t)EE * 4 * 4);        //   2 MB
    int*      deg    = (int*)alloc((size_t)NN * 4);
    int*      row_ptr= (int*)alloc((size_t)(NN + 1) * 4);
    int*      fill   = (int*)alloc((size_t)NN * 4);
    int*      dorder = (int*)alloc((size_t)NN * 4);
    int*      csum   = (int*)alloc((size_t)33 * 4);
    int*      srcp   = (int*)alloc((size_t)EE * 4);
    float4*   evp    = (float4*)alloc((size_t)EE * 16);          //   2 MB
    int*      kptab  = (int*)alloc((size_t)EE * 4);              // 0.5 MB
    unsigned* gtab   = (unsigned*)alloc((size_t)EE * 16);        //   2 MB (bf16 pairs)
    u16* xp_w1T   = (u16*)alloc((size_t)3 * 256 * 256 * 2);
    u16* xp_w2T   = (u16*)alloc((size_t)3 * 768 * 256 * 2);
    u16* rbf_wP   = (u16*)alloc((size_t)3 * 128 * 768 * 2);      // pair-interleaved bf16
    u16* vec_wT   = (u16*)alloc((size_t)3 * 512 * 256 * 2);
    u16* xv_w1T   = (u16*)alloc((size_t)3 * 256 * 512 * 2);
    u16* xv_w2T   = (u16*)alloc((size_t)3 * 768 * 256 * 2);
    u16* oe_w1T   = (u16*)alloc((size_t)128 * 256 * 2);
    (void)ws_size;

    u16*   h1b   = t1b;
    u16*   hcatb = xhb;
    float* heng  = vdot;
    u16*   xb    = xlnb;

    // ---- setup ----
    k_wt_all<<<2432, 256, 0, stream>>>(xp_w1, xp_w2, rbf_w, vec_w, xv_w1, xv_w2, oe_w1,
                                       xp_w1T, xp_w2T, rbf_wP, vec_wT, xv_w1T, xv_w2T, oe_w1T);
    k_zero<<<(36 * 1024 * 1024 / 16 + 255) / 256, 256, 0, stream>>>(vecA, 36 * 1024 * 1024 / 16);
    k_zero<<<8, 256, 0, stream>>>((float*)deg, NN / 4);
    k_init_ln<<<NN, 256, 0, stream>>>(atom_emb, z, ln_w, ln_b, x, xlnb);
    k_geom_hist<<<EE / 256, 256, 0, stream>>>(pos, ei, ev, deg);
    k_scan1<<<32, 256, 0, stream>>>(deg, row_ptr, csum);
    k_scan2<<<1, 64, 0, stream>>>(csum);
    k_scan3<<<32, 256, 0, stream>>>(csum, row_ptr, fill);
    k_sort<<<1, 256, 0, stream>>>(deg, dorder);
    k_scatter<<<EE / 256, 256, 0, stream>>>(ei, ev, fill, srcp, evp, kptab, gtab);

    for (int l = 0; l < LL; ++l) {
        // ---- PaiNNMessage ----
        k_gemm<1, 1, 32, 64><<<dim3(4, NN / 32), 256, 0, stream>>>(
            xlnb, xp_w1T + (size_t)l * 256 * 256, xp_b1 + l * HH, t1b, NN, 256, 256);
        k_gemm<1, 0, 32, 128><<<dim3(6, NN / 32), 256, 0, stream>>>(
            t1b, xp_w2T + (size_t)l * 768 * 256, xp_b2 + l * 768, xhb, NN, 256, 768);
        k_msg<<<NN / MSG_WAVES, 64 * MSG_WAVES, 0, stream>>>(
            xhb, vb, srcp, evp, row_ptr, kptab, gtab,
            rbf_wP + (size_t)l * 128 * 768, rbf_b + l * 768, x, vecA, vecMb, dorder);

        // ---- PaiNNUpdate ----
        k_gemm<1, 0, 64, 128><<<dim3(4, 3 * NN / 64), 256, 0, stream>>>(
            vecMb, vec_wT + (size_t)l * 512 * 256, nullptr, vpb, 3 * NN, 256, 512);
        k_vecdot<<<NN / 8, 256, 0, stream>>>(vpb, x, vdot, hcatb);
        k_gemm<1, 1, 32, 64><<<dim3(4, NN / 32), 256, 0, stream>>>(
            hcatb, xv_w1T + (size_t)l * 256 * 512, xv_b1 + l * HH, h1b, NN, 512, 256);
        k_gemm<1, 0, 32, 128><<<dim3(6, NN / 32), 256, 0, stream>>>(
            h1b, xv_w2T + (size_t)l * 768 * 256, xv_b2 + l * 768, houtb, NN, 256, 768);
        bool last = (l == LL - 1);
        k_update_out<<<NN / 8, 256, 0, stream>>>(
            houtb, vdot, vpb, x, vecMb, vecA, vb,
            last ? nullptr : ln_w + (l + 1) * HH,
            last ? nullptr : ln_b + (l + 1) * HH, xlnb);
    }

    // ---- energy head ----
    k_gemm<0, 1, 32, 64><<<dim3(2, NN / 32), 256, 0, stream>>>(
        xb, oe_w1T, oe_b1, heng, NN, 256, 128);
    k_zero<<<1, 256, 0, stream>>>(out, NGG / 4);
    k_energy2<<<32, 256, 0, stream>>>(heng, oe_w2, oe_b2, batch, out);
}